// Round 6
// baseline (320.939 us; speedup 1.0000x reference)
//
#include <hip/hip_runtime.h>
#include <hip/hip_bf16.h>

#define N_Z 16384
#define M_E 4096
#define DIM 256
#define NBZ 8192                      // fine z-buckets (query bound uses these)
#define NBE 2048                      // coarse e-sort buckets (grouping only)
#define BMIN (-6.0f)
#define ZSCALE ((float)NBZ / 12.0f)
#define ESCALE ((float)NBE / 12.0f)
#define BWZ (12.0f / (float)NBZ)      // exact: 3*2^-11

typedef __bf16 bf16x8 __attribute__((ext_vector_type(8)));
typedef float f32x4 __attribute__((ext_vector_type(4)));

__device__ __forceinline__ unsigned short f2bf(float f) {
  unsigned u = __float_as_uint(f);
  u = (u + 0x7FFFu + ((u >> 16) & 1u)) >> 16;
  return (unsigned short)u;
}

__device__ __forceinline__ void gl2lds16(const void* g, void* s) {
  __builtin_amdgcn_global_load_lds(
      (const __attribute__((address_space(1))) unsigned*)g,
      (__attribute__((address_space(3))) unsigned*)s, 16, 0, 0);
}

// bucket edges edge(k) = BMIN + k*BWZ are EXACT in f32 ((3k-12288)*2^-11),
// so fix up the inexact *ZSCALE rounding to make slice bounds sound.
__device__ __forceinline__ int bucketFixZ(float v) {
  int b = (int)((v - BMIN) * ZSCALE);
  b = min(max(b, 0), NBZ - 1);
  while (b > 0 && v < BMIN + (float)b * BWZ) --b;
  while (b < NBZ - 1 && v >= BMIN + (float)(b + 1) * BWZ) ++b;
  return b;
}
__device__ __forceinline__ int bucketE(float v) {  // grouping only, no exactness needed
  int b = (int)((v - BMIN) * ESCALE);
  return min(max(b, 0), NBE - 1);
}

// ---------------- init ----------------
__global__ void init_kernel(unsigned* __restrict__ d2min, float* __restrict__ wise_part,
                            float* __restrict__ z2, float* __restrict__ e2) {
  int i = blockIdx.x * blockDim.x + threadIdx.x;
  if (i < M_E) d2min[i] = 0x7F800000u;
  if (i < 64) wise_part[i] = 0.0f;
  if (i < N_Z) z2[i] = 0.0f;
  if (i < M_E) e2[i] = 0.0f;
}

// ---------------- fused prep: read once -> bf16 copy + transpose + row sq-norm ----------------
__global__ void prep_kernel(const float* __restrict__ in, float* __restrict__ outT,
                            unsigned short* __restrict__ outB, float* __restrict__ rsum, int R) {
  __shared__ float tile[32][33];
  __shared__ float rp[32];
  int r0 = blockIdx.x * 32, c0 = blockIdx.y * 32;
  int tx = threadIdx.x, ty = threadIdx.y;
  int lt = ty * 32 + tx;
  if (lt < 32) rp[lt] = 0.0f;
  __syncthreads();
#pragma unroll
  for (int i = 0; i < 4; ++i) {
    int rr = ty + 8 * i;
    float v = in[(size_t)(r0 + rr) * DIM + c0 + tx];
    tile[rr][tx] = v;
    outB[(size_t)(r0 + rr) * DIM + c0 + tx] = f2bf(v);
    atomicAdd(&rp[rr], v * v);
  }
  __syncthreads();
#pragma unroll
  for (int i = 0; i < 4; ++i)
    outT[(size_t)(c0 + ty + 8 * i) * R + r0 + tx] = tile[tx][ty + 8 * i];
  if (lt < 32) atomicAdd(&rsum[r0 + lt], rp[lt]);
}

// ---------------- fused bf16 GEMM (z . e^T) + min over n, per m ----------------
__global__ __launch_bounds__(256, 2) void gemm_min_kernel(
    const unsigned short* __restrict__ zb, const unsigned short* __restrict__ eb,
    const float* __restrict__ z2, const float* __restrict__ e2,
    unsigned* __restrict__ d2min) {
  __shared__ __align__(16) unsigned short lA[128 * 32];
  __shared__ __align__(16) unsigned short lB[128 * 32];

  const int t = threadIdx.x;
  const int w = t >> 6;
  const int l = t & 63;
  const int wr = w >> 1, wc = w & 1;
  int flat = blockIdx.y * 32 + blockIdx.x;
  int nf = (flat >> 3) + (flat & 7) * 512;
  const int tileM = (nf & 31) * 128;
  const int tileN = (nf >> 5) * 128;
  const int l15 = l & 15;
  const int kgr = l >> 4;

  f32x4 acc[4][4];
#pragma unroll
  for (int i = 0; i < 4; ++i)
#pragma unroll
    for (int j = 0; j < 4; ++j) acc[i][j] = (f32x4){0.f, 0.f, 0.f, 0.f};

#pragma unroll 1
  for (int k0 = 0; k0 < DIM; k0 += 32) {
#pragma unroll
    for (int i = 0; i < 2; ++i) {
      int c = i * 256 + t;
      int row = c >> 2;
      int kc = c & 3;
      int ldsbase = (i * 256 + (t & ~63)) * 8;
      gl2lds16(zb + (size_t)(tileN + row) * DIM + (k0 + kc * 8), &lA[ldsbase]);
      gl2lds16(eb + (size_t)(tileM + row) * DIM + (k0 + kc * 8), &lB[ldsbase]);
    }
    __syncthreads();

    bf16x8 a[4], b[4];
#pragma unroll
    for (int mi = 0; mi < 4; ++mi)
      a[mi] = *(const bf16x8*)&lA[(wr * 64 + mi * 16 + l15) * 32 + kgr * 8];
#pragma unroll
    for (int ni = 0; ni < 4; ++ni)
      b[ni] = *(const bf16x8*)&lB[(wc * 64 + ni * 16 + l15) * 32 + kgr * 8];
#pragma unroll
    for (int mi = 0; mi < 4; ++mi)
#pragma unroll
      for (int ni = 0; ni < 4; ++ni)
        acc[mi][ni] = __builtin_amdgcn_mfma_f32_16x16x32_bf16(a[mi], b[ni], acc[mi][ni], 0, 0, 0);
    __syncthreads();
  }

  float* z2s = (float*)lA;
  if (t < 128) z2s[t] = z2[tileN + t];
  __syncthreads();

#pragma unroll
  for (int ni = 0; ni < 4; ++ni) {
    float v = 3.4e38f;
#pragma unroll
    for (int mi = 0; mi < 4; ++mi)
#pragma unroll
      for (int r = 0; r < 4; ++r) {
        int rloc = wr * 64 + mi * 16 + kgr * 4 + r;
        v = fminf(v, z2s[rloc] - 2.0f * acc[mi][ni][r]);
      }
    v = fminf(v, __shfl_xor(v, 16));
    v = fminf(v, __shfl_xor(v, 32));
    if (l < 16) {
      int m = tileM + wc * 64 + ni * 16 + l;
      float d2 = v + e2[m];
      atomicMin(&d2min[m], __float_as_uint(d2));
    }
  }
}

// exclusive scan over arr[K*1024] with K buckets/thread; wsum = 16 scratch words
template <int K>
__device__ __forceinline__ void excl_scan_k(unsigned* arr, int t, unsigned* wsum) {
  unsigned c[K];
  unsigned ts = 0;
#pragma unroll
  for (int i = 0; i < K; ++i) { c[i] = arr[K * t + i]; ts += c[i]; }
  unsigned s = ts;
#pragma unroll
  for (int o = 1; o < 64; o <<= 1) {
    unsigned v = __shfl_up(s, o);
    if ((t & 63) >= o) s += v;
  }
  if ((t & 63) == 63) wsum[t >> 6] = s;
  __syncthreads();
  if (t == 0) {
    unsigned a = 0;
#pragma unroll
    for (int i = 0; i < 16; ++i) { unsigned v = wsum[i]; wsum[i] = a; a += v; }
  }
  __syncthreads();
  unsigned base = wsum[t >> 6] + (s - ts);
#pragma unroll
  for (int i = 0; i < K; ++i) { arr[K * t + i] = base; base += c[i]; }
  __syncthreads();
}

// ---------------- wise4: one block per dim; fine buckets, full column in LDS ----------------
// LDS 120KB: zs[16384] | zoff[8192] | eoff[2048] | esidx[4096] (wsum aliases esidx).
__global__ __launch_bounds__(1024) void wise4_kernel(
    const float* __restrict__ zT, const float* __restrict__ eT,
    float* __restrict__ wise_part) {
  extern __shared__ __align__(16) char smem[];
  float* zs = (float*)smem;                          // 16384 f  (64K)
  unsigned* zoff = (unsigned*)(smem + 65536);        // 8192 u   (32K)
  unsigned* eoff = zoff + NBZ;                       // 2048 u   (8K)
  unsigned* esidx = eoff + NBE;                      // 4096 u   (16K)
  unsigned* wsum = esidx;                            // alias (16) — esidx written after scans

  const int d = blockIdx.x, t = threadIdx.x;

  for (int i = t; i < NBZ + NBE; i += 1024) zoff[i] = 0u;  // zoff,eoff contiguous
  __syncthreads();

  // load z column (16/thread, coalesced), fine histogram
  float zv[16];
  int zbk[16];
  const float4* p = (const float4*)(zT + (size_t)d * N_Z);
#pragma unroll
  for (int i = 0; i < 4; ++i) {
    float4 v = p[i * 1024 + t];
    zv[4 * i + 0] = v.x; zv[4 * i + 1] = v.y; zv[4 * i + 2] = v.z; zv[4 * i + 3] = v.w;
  }
#pragma unroll
  for (int i = 0; i < 16; ++i) {
    zbk[i] = bucketFixZ(zv[i]);
    atomicAdd(&zoff[zbk[i]], 1u);
  }

  // load e column (4/thread, coalesced), coarse histogram
  const float* ec = eT + (size_t)d * M_E;
  float ev4[4];
  int ebk[4];
#pragma unroll
  for (int i = 0; i < 4; ++i) {
    ev4[i] = ec[i * 1024 + t];
    ebk[i] = bucketE(ev4[i]);
    atomicAdd(&eoff[ebk[i]], 1u);
  }
  __syncthreads();

  excl_scan_k<8>(zoff, t, wsum);
  excl_scan_k<2>(eoff, t, wsum);

  // scatter z values (fine buckets); scatter e indices (coarse buckets)
#pragma unroll
  for (int i = 0; i < 16; ++i) {
    unsigned pos = atomicAdd(&zoff[zbk[i]], 1u);
    zs[pos] = zv[i];
  }
#pragma unroll
  for (int i = 0; i < 4; ++i) {
    unsigned pos = atomicAdd(&eoff[ebk[i]], 1u);
    esidx[pos] = (unsigned)(i * 1024 + t);
  }
  __syncthreads();
  // zoff[b] = end(b); start(b) = b ? zoff[b-1] : 0

  float accq = 0.0f;
#pragma unroll 1
  for (int q = 0; q < 4; ++q) {
    int slot = q * 1024 + t;            // bucket-sorted order -> coherent lanes
    unsigned orig = esidx[slot];
    float ev = ec[orig];                // gather within L1-hot 16KB column
    int b0 = bucketFixZ(ev);
    unsigned s0 = b0 ? zoff[b0 - 1] : 0u;
    unsigned s1 = zoff[b0];
    float best2;
    {  // seeds: genuine z members adjacent in bucket order
      unsigned js = min(s0, (unsigned)(N_Z - 1));
      float dd = zs[js] - ev;
      best2 = dd * dd;
      if (s0 > 0) { dd = zs[s0 - 1] - ev; best2 = fminf(best2, dd * dd); }
    }
    for (unsigned j = s0; j < s1; ++j) {
      float dd = zs[j] - ev;
      best2 = fminf(best2, dd * dd);
    }
    for (int r = 1; r < NBZ; ++r) {
      int bl = b0 - r, br = b0 + r;
      float edgeL = BMIN + (float)(bl + 1) * BWZ;  // all z in bl <= edgeL <= ev
      float edgeR = BMIN + (float)br * BWZ;        // all z in br >= edgeR >= ev
      float dL = ev - edgeL, dR = edgeR - ev;
      bool doL = (bl >= 0) && (dL * dL < best2);
      bool doR = (br < NBZ) && (dR * dR < best2);
      if (!doL && !doR) break;
      if (doL) {
        unsigned a0 = bl ? zoff[bl - 1] : 0u, a1 = zoff[bl];
        for (unsigned j = a0; j < a1; ++j) {
          float dd = zs[j] - ev;
          best2 = fminf(best2, dd * dd);
        }
      }
      if (doR) {
        unsigned a0 = zoff[br - 1], a1 = zoff[br];
        for (unsigned j = a0; j < a1; ++j) {
          float dd = zs[j] - ev;
          best2 = fminf(best2, dd * dd);
        }
      }
    }
    accq += best2;
  }

  // block reduce -> one atomic; reuse zoff[0:16] as scratch (zs/zoff done)
#pragma unroll
  for (int o = 32; o; o >>= 1) accq += __shfl_down(accq, o);
  __syncthreads();
  if ((t & 63) == 0) zoff[t >> 6] = __float_as_uint(accq);
  __syncthreads();
  if (t == 0) {
    float ssum = 0.0f;
#pragma unroll
    for (int i = 0; i < 16; ++i) ssum += __uint_as_float(zoff[i]);
    atomicAdd(&wise_part[d & 63], ssum);
  }
}

// ---------------- final reduce ----------------
__global__ void final_kernel(const unsigned* __restrict__ d2min,
                             const float* __restrict__ wise_part, float* __restrict__ out) {
  __shared__ float red[4];
  int t = threadIdx.x;
  float s = 0.0f;
  for (int m = t; m < M_E; m += 256) s += __uint_as_float(d2min[m]);
#pragma unroll
  for (int off = 32; off; off >>= 1) s += __shfl_down(s, off);
  if ((t & 63) == 0) red[t >> 6] = s;
  __syncthreads();
  if (t == 0) {
    float tot = red[0] + red[1] + red[2] + red[3];
    out[0] = tot / (float)M_E;
    float w = 0.0f;
    for (int i = 0; i < 64; ++i) w += wise_part[i];
    out[1] = w / ((float)M_E * (float)DIM);
  }
}

extern "C" void kernel_launch(void* const* d_in, const int* in_sizes, int n_in,
                              void* d_out, int out_size, void* d_ws, size_t ws_size,
                              hipStream_t stream) {
  const float* z = (const float*)d_in[0];
  const float* e = (const float*)d_in[1];
  float* out = (float*)d_out;

  char* ws = (char*)d_ws;
  unsigned short* zb = (unsigned short*)ws;                 // 8 MiB
  unsigned short* eb = (unsigned short*)(ws + 8388608);     // 2 MiB
  float* z2 = (float*)(ws + 10485760);                      // 64 KiB
  float* e2 = (float*)(ws + 10551296);                      // 16 KiB
  unsigned* d2min = (unsigned*)(ws + 10567680);             // 16 KiB
  float* wise_part = (float*)(ws + 10584064);               // 256 B
  float* zT = (float*)(ws + 11534336);                      // 16 MiB
  float* eT = (float*)(ws + 28311552);                      // 4 MiB -> 32505856

  const size_t LDS_WISE = 65536 + NBZ * 4 + NBE * 4 + M_E * 4;  // 122880 B
  static int attr_done = 0;
  if (!attr_done) {
    (void)hipFuncSetAttribute((const void*)wise4_kernel,
                              hipFuncAttributeMaxDynamicSharedMemorySize, (int)LDS_WISE);
    attr_done = 1;
  }

  init_kernel<<<64, 256, 0, stream>>>(d2min, wise_part, z2, e2);
  prep_kernel<<<dim3(N_Z / 32, DIM / 32), dim3(32, 8), 0, stream>>>(z, zT, zb, z2, N_Z);
  prep_kernel<<<dim3(M_E / 32, DIM / 32), dim3(32, 8), 0, stream>>>(e, eT, eb, e2, M_E);
  gemm_min_kernel<<<dim3(32, 128), 256, 0, stream>>>(zb, eb, z2, e2, d2min);
  wise4_kernel<<<DIM, 1024, LDS_WISE, stream>>>(zT, eT, wise_part);
  final_kernel<<<1, 256, 0, stream>>>(d2min, wise_part, out);
}

// Round 7
// 184.718 us; speedup vs baseline: 1.7374x; 1.7374x over previous
//
#include <hip/hip_runtime.h>
#include <hip/hip_bf16.h>

#define N_Z 16384
#define M_E 4096
#define DIM 256
#define NB5 1024                      // wise buckets (monotone map)
#define BMIN (-6.0f)
#define SCALE5 ((float)NB5 / 12.0f)

typedef __bf16 bf16x8 __attribute__((ext_vector_type(8)));
typedef float f32x4 __attribute__((ext_vector_type(4)));

__device__ __forceinline__ unsigned short f2bf(float f) {
  unsigned u = __float_as_uint(f);
  u = (u + 0x7FFFu + ((u >> 16) & 1u)) >> 16;
  return (unsigned short)u;
}

__device__ __forceinline__ void gl2lds16(const void* g, void* s) {
  __builtin_amdgcn_global_load_lds(
      (const __attribute__((address_space(1))) unsigned*)g,
      (__attribute__((address_space(3))) unsigned*)s, 16, 0, 0);
}

// order-preserving float<->uint map
__device__ __forceinline__ unsigned fmap(float f) {
  unsigned u = __float_as_uint(f);
  return (u & 0x80000000u) ? ~u : (u | 0x80000000u);
}
__device__ __forceinline__ float funmap(unsigned u) {
  return __uint_as_float((u & 0x80000000u) ? (u ^ 0x80000000u) : ~u);
}
// MONOTONE bucket map (v<w => bucket(v)<=bucket(w)); exactness needs only monotonicity
__device__ __forceinline__ int bucket5(float v) {
  int b = (int)((v - BMIN) * SCALE5);
  return min(max(b, 0), NB5 - 1);
}

// ---------------- init ----------------
__global__ void init_kernel(unsigned* __restrict__ d2min, float* __restrict__ wise_part,
                            float* __restrict__ z2, float* __restrict__ e2) {
  int i = blockIdx.x * blockDim.x + threadIdx.x;
  if (i < M_E) d2min[i] = 0x7F800000u;
  if (i < 64) wise_part[i] = 0.0f;
  if (i < N_Z) z2[i] = 0.0f;
  if (i < M_E) e2[i] = 0.0f;
}

// ---------------- fused prep: read once -> bf16 copy + transpose + row sq-norm ----------------
__global__ void prep_kernel(const float* __restrict__ in, float* __restrict__ outT,
                            unsigned short* __restrict__ outB, float* __restrict__ rsum, int R) {
  __shared__ float tile[32][33];
  __shared__ float rp[32];
  int r0 = blockIdx.x * 32, c0 = blockIdx.y * 32;
  int tx = threadIdx.x, ty = threadIdx.y;
  int lt = ty * 32 + tx;
  if (lt < 32) rp[lt] = 0.0f;
  __syncthreads();
#pragma unroll
  for (int i = 0; i < 4; ++i) {
    int rr = ty + 8 * i;
    float v = in[(size_t)(r0 + rr) * DIM + c0 + tx];
    tile[rr][tx] = v;
    outB[(size_t)(r0 + rr) * DIM + c0 + tx] = f2bf(v);
    atomicAdd(&rp[rr], v * v);
  }
  __syncthreads();
#pragma unroll
  for (int i = 0; i < 4; ++i)
    outT[(size_t)(c0 + ty + 8 * i) * R + r0 + tx] = tile[tx][ty + 8 * i];
  if (lt < 32) atomicAdd(&rsum[r0 + lt], rp[lt]);
}

// ---------------- fused bf16 GEMM (z . e^T) + min over n, per m ----------------
// BK=64: 4 K-iters (half the barriers of BK=32). Fragment ds_read_b128 at row
// stride 128B would be 16-way bank conflict -> XOR swizzle: LDS dest stays
// linear (gl2lds16 rule), global SOURCE chunk kc^=(row&7), read side same XOR.
__global__ __launch_bounds__(256, 2) void gemm_min_kernel(
    const unsigned short* __restrict__ zb, const unsigned short* __restrict__ eb,
    const float* __restrict__ z2, const float* __restrict__ e2,
    unsigned* __restrict__ d2min) {
  __shared__ __align__(16) unsigned short lA[128 * 64];
  __shared__ __align__(16) unsigned short lB[128 * 64];

  const int t = threadIdx.x;
  const int w = t >> 6;
  const int l = t & 63;
  const int wr = w >> 1, wc = w & 1;
  int flat = blockIdx.y * 32 + blockIdx.x;
  int nf = (flat >> 3) + (flat & 7) * 512;
  const int tileM = (nf & 31) * 128;
  const int tileN = (nf >> 5) * 128;
  const int l15 = l & 15;
  const int kgr = l >> 4;

  f32x4 acc[4][4];
#pragma unroll
  for (int i = 0; i < 4; ++i)
#pragma unroll
    for (int j = 0; j < 4; ++j) acc[i][j] = (f32x4){0.f, 0.f, 0.f, 0.f};

#pragma unroll 1
  for (int k0 = 0; k0 < DIM; k0 += 64) {
    // stage 16KB per matrix: 1024 chunks of 16B, 4 per thread
#pragma unroll
    for (int i = 0; i < 4; ++i) {
      int c = i * 256 + t;
      int row = c >> 3;           // 8 chunks per 64-elem row
      int kc = c & 7;
      int kcs = kc ^ (row & 7);   // pre-swizzled global source
      int ldsbase = (i * 256 + (t & ~63)) * 8;  // wave-uniform, elements
      gl2lds16(zb + (size_t)(tileN + row) * DIM + (k0 + kcs * 8), &lA[ldsbase]);
      gl2lds16(eb + (size_t)(tileM + row) * DIM + (k0 + kcs * 8), &lB[ldsbase]);
    }
    __syncthreads();

#pragma unroll
    for (int kk = 0; kk < 2; ++kk) {
      bf16x8 a[4], b[4];
      const int kcr = kk * 4 + kgr;
#pragma unroll
      for (int mi = 0; mi < 4; ++mi) {
        int row = wr * 64 + mi * 16 + l15;
        a[mi] = *(const bf16x8*)&lA[row * 64 + ((kcr ^ (row & 7)) * 8)];
      }
#pragma unroll
      for (int ni = 0; ni < 4; ++ni) {
        int row = wc * 64 + ni * 16 + l15;
        b[ni] = *(const bf16x8*)&lB[row * 64 + ((kcr ^ (row & 7)) * 8)];
      }
#pragma unroll
      for (int mi = 0; mi < 4; ++mi)
#pragma unroll
        for (int ni = 0; ni < 4; ++ni)
          acc[mi][ni] = __builtin_amdgcn_mfma_f32_16x16x32_bf16(a[mi], b[ni], acc[mi][ni], 0, 0, 0);
    }
    __syncthreads();
  }

  float* z2s = (float*)lA;
  if (t < 128) z2s[t] = z2[tileN + t];
  __syncthreads();

#pragma unroll
  for (int ni = 0; ni < 4; ++ni) {
    float v = 3.4e38f;
#pragma unroll
    for (int mi = 0; mi < 4; ++mi)
#pragma unroll
      for (int r = 0; r < 4; ++r) {
        int rloc = wr * 64 + mi * 16 + kgr * 4 + r;
        v = fminf(v, z2s[rloc] - 2.0f * acc[mi][ni][r]);
      }
    v = fminf(v, __shfl_xor(v, 16));
    v = fminf(v, __shfl_xor(v, 32));
    if (l < 16) {
      int m = tileM + wc * 64 + ni * 16 + l;
      float d2 = v + e2[m];
      atomicMin(&d2min[m], __float_as_uint(d2));
    }
  }
}

// ---------------- wise5: one block per dim; prefix-max/suffix-min tables ----------------
// LDS 76KB: zs[16384] | zoff[1024] | pmax[1024] | psminN[1024]  -> 2 blocks/CU.
// Nearest z to query in bucket b0 is: in b0's slice, OR max z of buckets<b0
// (= pmax[b0-1]), OR min z of buckets>b0 (= ~psminN[b0+1]). Exact; no walks.
__global__ __launch_bounds__(1024) void wise5_kernel(
    const float* __restrict__ zT, const float* __restrict__ eT,
    float* __restrict__ wise_part) {
  extern __shared__ __align__(16) char smem[];
  float* zs = (float*)smem;                        // 16384 f (64K)
  unsigned* zoff = (unsigned*)(smem + 65536);      // 1024 u
  unsigned* pmax = zoff + NB5;                     // 1024 u
  unsigned* psminN = pmax + NB5;                   // 1024 u (max of ~fmap = suffix min)
  __shared__ unsigned scr[16];

  const int d = blockIdx.x, t = threadIdx.x;
  const int lane = t & 63, wid = t >> 6;

  zoff[t] = 0u; pmax[t] = 0u; psminN[t] = 0u;
  __syncthreads();

  // load z column (16/thread, coalesced), histogram + bucket max/min
  float zv[16];
  int zbk[16];
  const float4* p = (const float4*)(zT + (size_t)d * N_Z);
#pragma unroll
  for (int i = 0; i < 4; ++i) {
    float4 v = p[i * 1024 + t];
    zv[4 * i + 0] = v.x; zv[4 * i + 1] = v.y; zv[4 * i + 2] = v.z; zv[4 * i + 3] = v.w;
  }
#pragma unroll
  for (int i = 0; i < 16; ++i) {
    zbk[i] = bucket5(zv[i]);
    unsigned u = fmap(zv[i]);
    atomicAdd(&zoff[zbk[i]], 1u);
    atomicMax(&pmax[zbk[i]], u);
    atomicMax(&psminN[zbk[i]], ~u);
  }
  __syncthreads();

  // exclusive sum scan on zoff (1 bucket/thread)
  {
    unsigned c = zoff[t];
    unsigned incl = c;
#pragma unroll
    for (int o = 1; o < 64; o <<= 1) {
      unsigned v = __shfl_up(incl, o);
      if (lane >= o) incl += v;
    }
    if (lane == 63) scr[wid] = incl;
    __syncthreads();
    if (t == 0) {
      unsigned run = 0;
#pragma unroll
      for (int i = 0; i < 16; ++i) { unsigned v = scr[i]; scr[i] = run; run += v; }
    }
    __syncthreads();
    unsigned excl = scr[wid] + incl - c;
    __syncthreads();
    zoff[t] = excl;
  }
  __syncthreads();

  // scatter z into bucket-ordered LDS array; zoff[b] -> end(b)
#pragma unroll
  for (int i = 0; i < 16; ++i) {
    unsigned pos = atomicAdd(&zoff[zbk[i]], 1u);
    zs[pos] = zv[i];
  }

  // inclusive prefix-MAX scan on pmax (forward)
  {
    unsigned s = pmax[t];
    unsigned incl = s;
#pragma unroll
    for (int o = 1; o < 64; o <<= 1) {
      unsigned v = __shfl_up(incl, o);
      if (lane >= o) incl = max(incl, v);
    }
    __syncthreads();  // scr free (prev scan done)
    if (lane == 63) scr[wid] = incl;
    __syncthreads();
    if (t == 0) {
      unsigned run = 0;
#pragma unroll
      for (int i = 0; i < 16; ++i) { unsigned v = scr[i]; scr[i] = run; run = max(run, v); }
    }
    __syncthreads();
    pmax[t] = max(scr[wid], incl);
  }
  // inclusive suffix-MIN scan via prefix-max on ~fmap space, reversed index
  {
    int tr = NB5 - 1 - t;
    unsigned s = psminN[tr];
    unsigned incl = s;
#pragma unroll
    for (int o = 1; o < 64; o <<= 1) {
      unsigned v = __shfl_up(incl, o);
      if (lane >= o) incl = max(incl, v);
    }
    __syncthreads();
    if (lane == 63) scr[wid] = incl;
    __syncthreads();
    if (t == 0) {
      unsigned run = 0;
#pragma unroll
      for (int i = 0; i < 16; ++i) { unsigned v = scr[i]; scr[i] = run; run = max(run, v); }
    }
    __syncthreads();
    psminN[tr] = max(scr[wid], incl);
  }
  __syncthreads();

  // queries: 4/thread, coalesced; per query: 2 table lookups + own-slice scan
  const float* ec = eT + (size_t)d * M_E;
  float accq = 0.0f;
#pragma unroll 1
  for (int q = 0; q < 4; ++q) {
    float ev = ec[q * 1024 + t];
    int b0 = bucket5(ev);
    unsigned s0 = b0 ? zoff[b0 - 1] : 0u;
    unsigned s1 = zoff[b0];
    float best2 = 3.4e38f;
    if (b0 > 0) {
      unsigned u = pmax[b0 - 1];
      if (u) { float dd = funmap(u) - ev; best2 = dd * dd; }
    }
    if (b0 < NB5 - 1) {
      unsigned u = psminN[b0 + 1];
      if (u) { float dd = funmap(~u) - ev; best2 = fminf(best2, dd * dd); }
    }
    for (unsigned j = s0; j < s1; ++j) {
      float dd = zs[j] - ev;
      best2 = fminf(best2, dd * dd);
    }
    accq += best2;
  }

#pragma unroll
  for (int o = 32; o; o >>= 1) accq += __shfl_down(accq, o);
  __syncthreads();
  if (lane == 0) scr[wid] = __float_as_uint(accq);
  __syncthreads();
  if (t == 0) {
    float ssum = 0.0f;
#pragma unroll
    for (int i = 0; i < 16; ++i) ssum += __uint_as_float(scr[i]);
    atomicAdd(&wise_part[d & 63], ssum);
  }
}

// ---------------- final reduce ----------------
__global__ void final_kernel(const unsigned* __restrict__ d2min,
                             const float* __restrict__ wise_part, float* __restrict__ out) {
  __shared__ float red[4];
  int t = threadIdx.x;
  float s = 0.0f;
  for (int m = t; m < M_E; m += 256) s += __uint_as_float(d2min[m]);
#pragma unroll
  for (int off = 32; off; off >>= 1) s += __shfl_down(s, off);
  if ((t & 63) == 0) red[t >> 6] = s;
  __syncthreads();
  if (t == 0) {
    float tot = red[0] + red[1] + red[2] + red[3];
    out[0] = tot / (float)M_E;
    float w = 0.0f;
    for (int i = 0; i < 64; ++i) w += wise_part[i];
    out[1] = w / ((float)M_E * (float)DIM);
  }
}

extern "C" void kernel_launch(void* const* d_in, const int* in_sizes, int n_in,
                              void* d_out, int out_size, void* d_ws, size_t ws_size,
                              hipStream_t stream) {
  const float* z = (const float*)d_in[0];
  const float* e = (const float*)d_in[1];
  float* out = (float*)d_out;

  char* ws = (char*)d_ws;
  unsigned short* zb = (unsigned short*)ws;                 // 8 MiB
  unsigned short* eb = (unsigned short*)(ws + 8388608);     // 2 MiB
  float* z2 = (float*)(ws + 10485760);                      // 64 KiB
  float* e2 = (float*)(ws + 10551296);                      // 16 KiB
  unsigned* d2min = (unsigned*)(ws + 10567680);             // 16 KiB
  float* wise_part = (float*)(ws + 10584064);               // 256 B
  float* zT = (float*)(ws + 11534336);                      // 16 MiB
  float* eT = (float*)(ws + 28311552);                      // 4 MiB -> 32505856

  const size_t LDS_WISE = 65536 + 3 * NB5 * 4;              // 77824 B -> 2 blocks/CU
  static int attr_done = 0;
  if (!attr_done) {
    (void)hipFuncSetAttribute((const void*)wise5_kernel,
                              hipFuncAttributeMaxDynamicSharedMemorySize, (int)LDS_WISE);
    attr_done = 1;
  }

  init_kernel<<<64, 256, 0, stream>>>(d2min, wise_part, z2, e2);
  prep_kernel<<<dim3(N_Z / 32, DIM / 32), dim3(32, 8), 0, stream>>>(z, zT, zb, z2, N_Z);
  prep_kernel<<<dim3(M_E / 32, DIM / 32), dim3(32, 8), 0, stream>>>(e, eT, eb, e2, M_E);
  gemm_min_kernel<<<dim3(32, 128), 256, 0, stream>>>(zb, eb, z2, e2, d2min);
  wise5_kernel<<<DIM, 1024, LDS_WISE, stream>>>(zT, eT, wise_part);
  final_kernel<<<1, 256, 0, stream>>>(d2min, wise_part, out);
}

// Round 8
// 162.828 us; speedup vs baseline: 1.9710x; 1.1344x over previous
//
#include <hip/hip_runtime.h>
#include <hip/hip_bf16.h>

#define N_Z 16384
#define M_E 4096
#define DIM 256
#define NB5 1024                      // wise buckets (monotone map)
#define BMIN (-6.0f)
#define SCALE5 ((float)NB5 / 12.0f)

typedef __bf16 bf16x8 __attribute__((ext_vector_type(8)));
typedef float f32x4 __attribute__((ext_vector_type(4)));

__device__ __forceinline__ unsigned short f2bf(float f) {
  unsigned u = __float_as_uint(f);
  u = (u + 0x7FFFu + ((u >> 16) & 1u)) >> 16;
  return (unsigned short)u;
}

__device__ __forceinline__ void gl2lds16(const void* g, void* s) {
  __builtin_amdgcn_global_load_lds(
      (const __attribute__((address_space(1))) unsigned*)g,
      (__attribute__((address_space(3))) unsigned*)s, 16, 0, 0);
}

// order-preserving float<->uint map
__device__ __forceinline__ unsigned fmap(float f) {
  unsigned u = __float_as_uint(f);
  return (u & 0x80000000u) ? ~u : (u | 0x80000000u);
}
__device__ __forceinline__ float funmap(unsigned u) {
  return __uint_as_float((u & 0x80000000u) ? (u ^ 0x80000000u) : ~u);
}
// MONOTONE bucket map (v<w => bucket(v)<=bucket(w)); exactness needs only monotonicity
__device__ __forceinline__ int bucket5(float v) {
  int b = (int)((v - BMIN) * SCALE5);
  return min(max(b, 0), NB5 - 1);
}

// ---------------- init ----------------
__global__ void init_kernel(unsigned* __restrict__ d2min, float* __restrict__ wise_part,
                            float* __restrict__ z2, float* __restrict__ e2) {
  int i = blockIdx.x * blockDim.x + threadIdx.x;
  if (i < M_E) d2min[i] = 0x7F800000u;
  if (i < 64) wise_part[i] = 0.0f;
  if (i < N_Z) z2[i] = 0.0f;
  if (i < M_E) e2[i] = 0.0f;
}

// ---------------- fused prep: read once -> bf16 copy + transpose + row sq-norm ----------------
// row-sum via width-32 shfl reduce (NOT same-address LDS atomics: 32-way serialize)
__global__ void prep_kernel(const float* __restrict__ in, float* __restrict__ outT,
                            unsigned short* __restrict__ outB, float* __restrict__ rsum, int R) {
  __shared__ float tile[32][33];
  int r0 = blockIdx.x * 32, c0 = blockIdx.y * 32;
  int tx = threadIdx.x, ty = threadIdx.y;
#pragma unroll
  for (int i = 0; i < 4; ++i) {
    int rr = ty + 8 * i;
    float v = in[(size_t)(r0 + rr) * DIM + c0 + tx];
    tile[rr][tx] = v;
    outB[(size_t)(r0 + rr) * DIM + c0 + tx] = f2bf(v);
    float s = v * v;
#pragma unroll
    for (int o = 1; o < 32; o <<= 1) s += __shfl_xor(s, o);  // xor<32: stays in row group
    if (tx == 0) atomicAdd(&rsum[r0 + rr], s);
  }
  __syncthreads();
#pragma unroll
  for (int i = 0; i < 4; ++i)
    outT[(size_t)(c0 + ty + 8 * i) * R + r0 + tx] = tile[tx][ty + 8 * i];
}

// ---------------- fused bf16 GEMM (z . e^T) + min over n, per m ----------------
// BK=64, XOR-swizzled staging (linear LDS dest, pre-swizzled global source).
__global__ __launch_bounds__(256, 2) void gemm_min_kernel(
    const unsigned short* __restrict__ zb, const unsigned short* __restrict__ eb,
    const float* __restrict__ z2, const float* __restrict__ e2,
    unsigned* __restrict__ d2min) {
  __shared__ __align__(16) unsigned short lA[128 * 64];
  __shared__ __align__(16) unsigned short lB[128 * 64];

  const int t = threadIdx.x;
  const int w = t >> 6;
  const int l = t & 63;
  const int wr = w >> 1, wc = w & 1;
  int flat = blockIdx.y * 32 + blockIdx.x;
  int nf = (flat >> 3) + (flat & 7) * 512;
  const int tileM = (nf & 31) * 128;
  const int tileN = (nf >> 5) * 128;
  const int l15 = l & 15;
  const int kgr = l >> 4;

  f32x4 acc[4][4];
#pragma unroll
  for (int i = 0; i < 4; ++i)
#pragma unroll
    for (int j = 0; j < 4; ++j) acc[i][j] = (f32x4){0.f, 0.f, 0.f, 0.f};

#pragma unroll 1
  for (int k0 = 0; k0 < DIM; k0 += 64) {
#pragma unroll
    for (int i = 0; i < 4; ++i) {
      int c = i * 256 + t;
      int row = c >> 3;
      int kc = c & 7;
      int kcs = kc ^ (row & 7);
      int ldsbase = (i * 256 + (t & ~63)) * 8;
      gl2lds16(zb + (size_t)(tileN + row) * DIM + (k0 + kcs * 8), &lA[ldsbase]);
      gl2lds16(eb + (size_t)(tileM + row) * DIM + (k0 + kcs * 8), &lB[ldsbase]);
    }
    __syncthreads();

#pragma unroll
    for (int kk = 0; kk < 2; ++kk) {
      bf16x8 a[4], b[4];
      const int kcr = kk * 4 + kgr;
#pragma unroll
      for (int mi = 0; mi < 4; ++mi) {
        int row = wr * 64 + mi * 16 + l15;
        a[mi] = *(const bf16x8*)&lA[row * 64 + ((kcr ^ (row & 7)) * 8)];
      }
#pragma unroll
      for (int ni = 0; ni < 4; ++ni) {
        int row = wc * 64 + ni * 16 + l15;
        b[ni] = *(const bf16x8*)&lB[row * 64 + ((kcr ^ (row & 7)) * 8)];
      }
#pragma unroll
      for (int mi = 0; mi < 4; ++mi)
#pragma unroll
        for (int ni = 0; ni < 4; ++ni)
          acc[mi][ni] = __builtin_amdgcn_mfma_f32_16x16x32_bf16(a[mi], b[ni], acc[mi][ni], 0, 0, 0);
    }
    __syncthreads();
  }

  float* z2s = (float*)lA;
  if (t < 128) z2s[t] = z2[tileN + t];
  __syncthreads();

#pragma unroll
  for (int ni = 0; ni < 4; ++ni) {
    float v = 3.4e38f;
#pragma unroll
    for (int mi = 0; mi < 4; ++mi)
#pragma unroll
      for (int r = 0; r < 4; ++r) {
        int rloc = wr * 64 + mi * 16 + kgr * 4 + r;
        v = fminf(v, z2s[rloc] - 2.0f * acc[mi][ni][r]);
      }
    v = fminf(v, __shfl_xor(v, 16));
    v = fminf(v, __shfl_xor(v, 32));
    if (l < 16) {
      int m = tileM + wc * 64 + ni * 16 + l;
      float d2 = v + e2[m];
      atomicMin(&d2min[m], __float_as_uint(d2));
    }
  }
}

// ---------------- wise6: tables built by slice scan; lane-pair queries ----------------
// LDS 76KB: zs[16384] | zoff[1024] | pmax[1024] | psminN[1024] -> 2 blocks/CU.
__global__ __launch_bounds__(1024) void wise6_kernel(
    const float* __restrict__ zT, const float* __restrict__ eT,
    float* __restrict__ wise_part) {
  extern __shared__ __align__(16) char smem[];
  float* zs = (float*)smem;                        // 16384 f (64K)
  unsigned* zoff = (unsigned*)(smem + 65536);      // 1024 u
  unsigned* pmax = zoff + NB5;                     // 1024 u
  unsigned* psminN = pmax + NB5;                   // 1024 u
  __shared__ unsigned scr[16];

  const int d = blockIdx.x, t = threadIdx.x;
  const int lane = t & 63, wid = t >> 6;

  zoff[t] = 0u;
  __syncthreads();

  // load z column (16/thread, coalesced), histogram
  float zv[16];
  int zbk[16];
  const float4* p = (const float4*)(zT + (size_t)d * N_Z);
#pragma unroll
  for (int i = 0; i < 4; ++i) {
    float4 v = p[i * 1024 + t];
    zv[4 * i + 0] = v.x; zv[4 * i + 1] = v.y; zv[4 * i + 2] = v.z; zv[4 * i + 3] = v.w;
  }
#pragma unroll
  for (int i = 0; i < 16; ++i) {
    zbk[i] = bucket5(zv[i]);
    atomicAdd(&zoff[zbk[i]], 1u);
  }
  __syncthreads();

  // exclusive sum scan on zoff (1 bucket/thread)
  {
    unsigned c = zoff[t];
    unsigned incl = c;
#pragma unroll
    for (int o = 1; o < 64; o <<= 1) {
      unsigned v = __shfl_up(incl, o);
      if (lane >= o) incl += v;
    }
    if (lane == 63) scr[wid] = incl;
    __syncthreads();
    if (t == 0) {
      unsigned run = 0;
#pragma unroll
      for (int i = 0; i < 16; ++i) { unsigned v = scr[i]; scr[i] = run; run += v; }
    }
    __syncthreads();
    unsigned excl = scr[wid] + incl - c;
    __syncthreads();
    zoff[t] = excl;
  }
  __syncthreads();

  // scatter z into bucket-ordered LDS array; zoff[b] -> end(b)
#pragma unroll
  for (int i = 0; i < 16; ++i) {
    unsigned pos = atomicAdd(&zoff[zbk[i]], 1u);
    zs[pos] = zv[i];
  }
  __syncthreads();

  // per-bucket min/max from slice scan (no atomics): thread t owns bucket t
  {
    unsigned s0 = t ? zoff[t - 1] : 0u;
    unsigned s1 = zoff[t];
    unsigned mxU = 0u, mnN = 0u;
    for (unsigned j = s0; j < s1; ++j) {
      unsigned u = fmap(zs[j]);
      mxU = max(mxU, u);
      mnN = max(mnN, ~u);
    }
    pmax[t] = mxU;
    psminN[t] = mnN;
  }
  __syncthreads();

  // inclusive prefix-MAX scan on pmax (forward)
  {
    unsigned s = pmax[t];
    unsigned incl = s;
#pragma unroll
    for (int o = 1; o < 64; o <<= 1) {
      unsigned v = __shfl_up(incl, o);
      if (lane >= o) incl = max(incl, v);
    }
    __syncthreads();
    if (lane == 63) scr[wid] = incl;
    __syncthreads();
    if (t == 0) {
      unsigned run = 0;
#pragma unroll
      for (int i = 0; i < 16; ++i) { unsigned v = scr[i]; scr[i] = run; run = max(run, v); }
    }
    __syncthreads();
    pmax[t] = max(scr[wid], incl);
  }
  // inclusive suffix-MIN scan via prefix-max on ~fmap space, reversed index
  {
    int tr = NB5 - 1 - t;
    unsigned s = psminN[tr];
    unsigned incl = s;
#pragma unroll
    for (int o = 1; o < 64; o <<= 1) {
      unsigned v = __shfl_up(incl, o);
      if (lane >= o) incl = max(incl, v);
    }
    __syncthreads();
    if (lane == 63) scr[wid] = incl;
    __syncthreads();
    if (t == 0) {
      unsigned run = 0;
#pragma unroll
      for (int i = 0; i < 16; ++i) { unsigned v = scr[i]; scr[i] = run; run = max(run, v); }
    }
    __syncthreads();
    psminN[tr] = max(scr[wid], incl);
  }
  __syncthreads();

  // queries: lane pairs (2p,2p+1) share one query; stride-2 slice scan
  const float* ec = eT + (size_t)d * M_E;
  const int pr = t >> 1;
  const int sub = t & 1;
  float accq = 0.0f;
#pragma unroll 1
  for (int q = 0; q < 8; ++q) {
    int qi = q * 512 + pr;
    float ev = ec[qi];
    int b0 = bucket5(ev);
    unsigned s0 = b0 ? zoff[b0 - 1] : 0u;
    unsigned s1 = zoff[b0];
    float best2 = 3.4e38f;
    if (b0 > 0) {
      unsigned u = pmax[b0 - 1];
      if (u) { float dd = funmap(u) - ev; best2 = dd * dd; }
    }
    if (b0 < NB5 - 1) {
      unsigned u = psminN[b0 + 1];
      if (u) { float dd = funmap(~u) - ev; best2 = fminf(best2, dd * dd); }
    }
    for (unsigned j = s0 + sub; j < s1; j += 2) {
      float dd = zs[j] - ev;
      best2 = fminf(best2, dd * dd);
    }
    best2 = fminf(best2, __shfl_xor(best2, 1));
    if (sub == 0) accq += best2;
  }

#pragma unroll
  for (int o = 32; o; o >>= 1) accq += __shfl_down(accq, o);
  __syncthreads();
  if (lane == 0) scr[wid] = __float_as_uint(accq);
  __syncthreads();
  if (t == 0) {
    float ssum = 0.0f;
#pragma unroll
    for (int i = 0; i < 16; ++i) ssum += __uint_as_float(scr[i]);
    atomicAdd(&wise_part[d & 63], ssum);
  }
}

// ---------------- final reduce ----------------
__global__ void final_kernel(const unsigned* __restrict__ d2min,
                             const float* __restrict__ wise_part, float* __restrict__ out) {
  __shared__ float red[4];
  int t = threadIdx.x;
  float s = 0.0f;
  for (int m = t; m < M_E; m += 256) s += __uint_as_float(d2min[m]);
#pragma unroll
  for (int off = 32; off; off >>= 1) s += __shfl_down(s, off);
  if ((t & 63) == 0) red[t >> 6] = s;
  __syncthreads();
  if (t == 0) {
    float tot = red[0] + red[1] + red[2] + red[3];
    out[0] = tot / (float)M_E;
    float w = 0.0f;
    for (int i = 0; i < 64; ++i) w += wise_part[i];
    out[1] = w / ((float)M_E * (float)DIM);
  }
}

extern "C" void kernel_launch(void* const* d_in, const int* in_sizes, int n_in,
                              void* d_out, int out_size, void* d_ws, size_t ws_size,
                              hipStream_t stream) {
  const float* z = (const float*)d_in[0];
  const float* e = (const float*)d_in[1];
  float* out = (float*)d_out;

  char* ws = (char*)d_ws;
  unsigned short* zb = (unsigned short*)ws;                 // 8 MiB
  unsigned short* eb = (unsigned short*)(ws + 8388608);     // 2 MiB
  float* z2 = (float*)(ws + 10485760);                      // 64 KiB
  float* e2 = (float*)(ws + 10551296);                      // 16 KiB
  unsigned* d2min = (unsigned*)(ws + 10567680);             // 16 KiB
  float* wise_part = (float*)(ws + 10584064);               // 256 B
  float* zT = (float*)(ws + 11534336);                      // 16 MiB
  float* eT = (float*)(ws + 28311552);                      // 4 MiB -> 32505856

  const size_t LDS_WISE = 65536 + 3 * NB5 * 4;              // 77824 B -> 2 blocks/CU
  static int attr_done = 0;
  if (!attr_done) {
    (void)hipFuncSetAttribute((const void*)wise6_kernel,
                              hipFuncAttributeMaxDynamicSharedMemorySize, (int)LDS_WISE);
    attr_done = 1;
  }

  init_kernel<<<64, 256, 0, stream>>>(d2min, wise_part, z2, e2);
  prep_kernel<<<dim3(N_Z / 32, DIM / 32), dim3(32, 8), 0, stream>>>(z, zT, zb, z2, N_Z);
  prep_kernel<<<dim3(M_E / 32, DIM / 32), dim3(32, 8), 0, stream>>>(e, eT, eb, e2, M_E);
  gemm_min_kernel<<<dim3(32, 128), 256, 0, stream>>>(zb, eb, z2, e2, d2min);
  wise6_kernel<<<DIM, 1024, LDS_WISE, stream>>>(zT, eT, wise_part);
  final_kernel<<<1, 256, 0, stream>>>(d2min, wise_part, out);
}

// Round 9
// 143.691 us; speedup vs baseline: 2.2335x; 1.1332x over previous
//
#include <hip/hip_runtime.h>
#include <hip/hip_bf16.h>

#define N_Z 16384
#define M_E 4096
#define DIM 256
#define NB5 1024                      // wise buckets (monotone map)
#define BMIN (-6.0f)
#define SCALE5 ((float)NB5 / 12.0f)

typedef __bf16 bf16x8 __attribute__((ext_vector_type(8)));
typedef float f32x4 __attribute__((ext_vector_type(4)));

__device__ __forceinline__ unsigned short f2bf(float f) {
  unsigned u = __float_as_uint(f);
  u = (u + 0x7FFFu + ((u >> 16) & 1u)) >> 16;
  return (unsigned short)u;
}

__device__ __forceinline__ void gl2lds16(const void* g, void* s) {
  __builtin_amdgcn_global_load_lds(
      (const __attribute__((address_space(1))) unsigned*)g,
      (__attribute__((address_space(3))) unsigned*)s, 16, 0, 0);
}

// order-preserving float<->uint map
__device__ __forceinline__ unsigned fmap(float f) {
  unsigned u = __float_as_uint(f);
  return (u & 0x80000000u) ? ~u : (u | 0x80000000u);
}
__device__ __forceinline__ float funmap(unsigned u) {
  return __uint_as_float((u & 0x80000000u) ? (u ^ 0x80000000u) : ~u);
}
// MONOTONE bucket map (v<w => bucket(v)<=bucket(w)); exactness needs only monotonicity
__device__ __forceinline__ int bucket5(float v) {
  int b = (int)((v - BMIN) * SCALE5);
  return min(max(b, 0), NB5 - 1);
}

// ---------------- init ----------------
__global__ void init_kernel(unsigned* __restrict__ d2min, float* __restrict__ wise_part,
                            float* __restrict__ z2, float* __restrict__ e2) {
  int i = blockIdx.x * blockDim.x + threadIdx.x;
  if (i < M_E) d2min[i] = 0x7F800000u;
  if (i < 64) wise_part[i] = 0.0f;
  if (i < N_Z) z2[i] = 0.0f;
  if (i < M_E) e2[i] = 0.0f;
}

// ---------------- fused prep: read once -> bf16 copy + transpose + row sq-norm ----------------
__global__ void prep_kernel(const float* __restrict__ in, float* __restrict__ outT,
                            unsigned short* __restrict__ outB, float* __restrict__ rsum, int R) {
  __shared__ float tile[32][33];
  int r0 = blockIdx.x * 32, c0 = blockIdx.y * 32;
  int tx = threadIdx.x, ty = threadIdx.y;
#pragma unroll
  for (int i = 0; i < 4; ++i) {
    int rr = ty + 8 * i;
    float v = in[(size_t)(r0 + rr) * DIM + c0 + tx];
    tile[rr][tx] = v;
    outB[(size_t)(r0 + rr) * DIM + c0 + tx] = f2bf(v);
    float s = v * v;
#pragma unroll
    for (int o = 1; o < 32; o <<= 1) s += __shfl_xor(s, o);  // xor<32: stays in row group
    if (tx == 0) atomicAdd(&rsum[r0 + rr], s);
  }
  __syncthreads();
#pragma unroll
  for (int i = 0; i < 4; ++i)
    outT[(size_t)(c0 + ty + 8 * i) * R + r0 + tx] = tile[tx][ty + 8 * i];
}

// ---------------- fused bf16 GEMM (z . e^T) + min over n, per m ----------------
// BK=64, XOR-swizzled staging (linear LDS dest, pre-swizzled global source).
__global__ __launch_bounds__(256, 2) void gemm_min_kernel(
    const unsigned short* __restrict__ zb, const unsigned short* __restrict__ eb,
    const float* __restrict__ z2, const float* __restrict__ e2,
    unsigned* __restrict__ d2min) {
  __shared__ __align__(16) unsigned short lA[128 * 64];
  __shared__ __align__(16) unsigned short lB[128 * 64];

  const int t = threadIdx.x;
  const int w = t >> 6;
  const int l = t & 63;
  const int wr = w >> 1, wc = w & 1;
  int flat = blockIdx.y * 32 + blockIdx.x;
  int nf = (flat >> 3) + (flat & 7) * 512;
  const int tileM = (nf & 31) * 128;
  const int tileN = (nf >> 5) * 128;
  const int l15 = l & 15;
  const int kgr = l >> 4;

  f32x4 acc[4][4];
#pragma unroll
  for (int i = 0; i < 4; ++i)
#pragma unroll
    for (int j = 0; j < 4; ++j) acc[i][j] = (f32x4){0.f, 0.f, 0.f, 0.f};

#pragma unroll 1
  for (int k0 = 0; k0 < DIM; k0 += 64) {
#pragma unroll
    for (int i = 0; i < 4; ++i) {
      int c = i * 256 + t;
      int row = c >> 3;
      int kc = c & 7;
      int kcs = kc ^ (row & 7);
      int ldsbase = (i * 256 + (t & ~63)) * 8;
      gl2lds16(zb + (size_t)(tileN + row) * DIM + (k0 + kcs * 8), &lA[ldsbase]);
      gl2lds16(eb + (size_t)(tileM + row) * DIM + (k0 + kcs * 8), &lB[ldsbase]);
    }
    __syncthreads();

#pragma unroll
    for (int kk = 0; kk < 2; ++kk) {
      bf16x8 a[4], b[4];
      const int kcr = kk * 4 + kgr;
#pragma unroll
      for (int mi = 0; mi < 4; ++mi) {
        int row = wr * 64 + mi * 16 + l15;
        a[mi] = *(const bf16x8*)&lA[row * 64 + ((kcr ^ (row & 7)) * 8)];
      }
#pragma unroll
      for (int ni = 0; ni < 4; ++ni) {
        int row = wc * 64 + ni * 16 + l15;
        b[ni] = *(const bf16x8*)&lB[row * 64 + ((kcr ^ (row & 7)) * 8)];
      }
#pragma unroll
      for (int mi = 0; mi < 4; ++mi)
#pragma unroll
        for (int ni = 0; ni < 4; ++ni)
          acc[mi][ni] = __builtin_amdgcn_mfma_f32_16x16x32_bf16(a[mi], b[ni], acc[mi][ni], 0, 0, 0);
    }
    __syncthreads();
  }

  float* z2s = (float*)lA;
  if (t < 128) z2s[t] = z2[tileN + t];
  __syncthreads();

#pragma unroll
  for (int ni = 0; ni < 4; ++ni) {
    float v = 3.4e38f;
#pragma unroll
    for (int mi = 0; mi < 4; ++mi)
#pragma unroll
      for (int r = 0; r < 4; ++r) {
        int rloc = wr * 64 + mi * 16 + kgr * 4 + r;
        v = fminf(v, z2s[rloc] - 2.0f * acc[mi][ni][r]);
      }
    v = fminf(v, __shfl_xor(v, 16));
    v = fminf(v, __shfl_xor(v, 32));
    if (l < 16) {
      int m = tileM + wc * 64 + ni * 16 + l;
      float d2 = v + e2[m];
      atomicMin(&d2min[m], __float_as_uint(d2));
    }
  }
}

// ---------------- wise7: float4 over-scan queries + prefix tables ----------------
// LDS 76KB: zs[16384] | zoff[1024] | pmax[1024] | psminN[1024] -> 2 blocks/CU.
// Over-scan is EXACT: every element of zs is a genuine z value, so extra
// candidates can only tighten the min. (Tables are built WITHOUT over-scan.)
__global__ __launch_bounds__(1024) void wise7_kernel(
    const float* __restrict__ zT, const float* __restrict__ eT,
    float* __restrict__ wise_part) {
  extern __shared__ __align__(16) char smem[];
  float* zs = (float*)smem;                        // 16384 f (64K)
  unsigned* zoff = (unsigned*)(smem + 65536);      // 1024 u
  unsigned* pmax = zoff + NB5;                     // 1024 u
  unsigned* psminN = pmax + NB5;                   // 1024 u
  __shared__ unsigned scr[16];

  const int d = blockIdx.x, t = threadIdx.x;
  const int lane = t & 63, wid = t >> 6;

  zoff[t] = 0u;
  __syncthreads();

  // load z column (16/thread, coalesced), histogram
  float zv[16];
  int zbk[16];
  const float4* p = (const float4*)(zT + (size_t)d * N_Z);
#pragma unroll
  for (int i = 0; i < 4; ++i) {
    float4 v = p[i * 1024 + t];
    zv[4 * i + 0] = v.x; zv[4 * i + 1] = v.y; zv[4 * i + 2] = v.z; zv[4 * i + 3] = v.w;
  }
#pragma unroll
  for (int i = 0; i < 16; ++i) {
    zbk[i] = bucket5(zv[i]);
    atomicAdd(&zoff[zbk[i]], 1u);
  }
  __syncthreads();

  // exclusive sum scan on zoff (1 bucket/thread)
  {
    unsigned c = zoff[t];
    unsigned incl = c;
#pragma unroll
    for (int o = 1; o < 64; o <<= 1) {
      unsigned v = __shfl_up(incl, o);
      if (lane >= o) incl += v;
    }
    if (lane == 63) scr[wid] = incl;
    __syncthreads();
    if (t == 0) {
      unsigned run = 0;
#pragma unroll
      for (int i = 0; i < 16; ++i) { unsigned v = scr[i]; scr[i] = run; run += v; }
    }
    __syncthreads();
    unsigned excl = scr[wid] + incl - c;
    __syncthreads();
    zoff[t] = excl;
  }
  __syncthreads();

  // scatter z into bucket-ordered LDS array; zoff[b] -> end(b)
#pragma unroll
  for (int i = 0; i < 16; ++i) {
    unsigned pos = atomicAdd(&zoff[zbk[i]], 1u);
    zs[pos] = zv[i];
  }
  __syncthreads();

  // per-bucket min/max from exact slice scan (NO over-scan here)
  {
    unsigned s0 = t ? zoff[t - 1] : 0u;
    unsigned s1 = zoff[t];
    unsigned mxU = 0u, mnN = 0u;
    for (unsigned j = s0; j < s1; ++j) {
      unsigned u = fmap(zs[j]);
      mxU = max(mxU, u);
      mnN = max(mnN, ~u);
    }
    pmax[t] = mxU;
    psminN[t] = mnN;
  }
  __syncthreads();

  // inclusive prefix-MAX scan on pmax (forward)
  {
    unsigned s = pmax[t];
    unsigned incl = s;
#pragma unroll
    for (int o = 1; o < 64; o <<= 1) {
      unsigned v = __shfl_up(incl, o);
      if (lane >= o) incl = max(incl, v);
    }
    __syncthreads();
    if (lane == 63) scr[wid] = incl;
    __syncthreads();
    if (t == 0) {
      unsigned run = 0;
#pragma unroll
      for (int i = 0; i < 16; ++i) { unsigned v = scr[i]; scr[i] = run; run = max(run, v); }
    }
    __syncthreads();
    pmax[t] = max(scr[wid], incl);
  }
  // inclusive suffix-MIN scan via prefix-max on ~fmap space, reversed index
  {
    int tr = NB5 - 1 - t;
    unsigned s = psminN[tr];
    unsigned incl = s;
#pragma unroll
    for (int o = 1; o < 64; o <<= 1) {
      unsigned v = __shfl_up(incl, o);
      if (lane >= o) incl = max(incl, v);
    }
    __syncthreads();
    if (lane == 63) scr[wid] = incl;
    __syncthreads();
    if (t == 0) {
      unsigned run = 0;
#pragma unroll
      for (int i = 0; i < 16; ++i) { unsigned v = scr[i]; scr[i] = run; run = max(run, v); }
    }
    __syncthreads();
    psminN[tr] = max(scr[wid], incl);
  }
  __syncthreads();

  // queries: 1/thread x4, float4 over-scan of own slice + 2 table lookups
  const float* ec = eT + (size_t)d * M_E;
  float accq = 0.0f;
#pragma unroll 1
  for (int q = 0; q < 4; ++q) {
    float ev = ec[q * 1024 + t];
    int b0 = bucket5(ev);
    unsigned s0 = b0 ? zoff[b0 - 1] : 0u;
    unsigned s1 = zoff[b0];
    float best2 = 3.4e38f;
    if (b0 > 0) {
      unsigned u = pmax[b0 - 1];
      if (u) { float dd = funmap(u) - ev; best2 = dd * dd; }
    }
    if (b0 < NB5 - 1) {
      unsigned u = psminN[b0 + 1];
      if (u) { float dd = funmap(~u) - ev; best2 = fminf(best2, dd * dd); }
    }
    for (unsigned j = s0 & ~3u; j < s1; j += 4) {
      float4 zz = *(const float4*)&zs[j];
      float d0 = zz.x - ev, d1 = zz.y - ev;
      float d2 = zz.z - ev, d3 = zz.w - ev;
      best2 = fminf(best2, fminf(fminf(d0 * d0, d1 * d1), fminf(d2 * d2, d3 * d3)));
    }
    accq += best2;
  }

#pragma unroll
  for (int o = 32; o; o >>= 1) accq += __shfl_down(accq, o);
  __syncthreads();
  if (lane == 0) scr[wid] = __float_as_uint(accq);
  __syncthreads();
  if (t == 0) {
    float ssum = 0.0f;
#pragma unroll
    for (int i = 0; i < 16; ++i) ssum += __uint_as_float(scr[i]);
    atomicAdd(&wise_part[d & 63], ssum);
  }
}

// ---------------- final reduce ----------------
__global__ void final_kernel(const unsigned* __restrict__ d2min,
                             const float* __restrict__ wise_part, float* __restrict__ out) {
  __shared__ float red[4];
  int t = threadIdx.x;
  float s = 0.0f;
  for (int m = t; m < M_E; m += 256) s += __uint_as_float(d2min[m]);
#pragma unroll
  for (int off = 32; off; off >>= 1) s += __shfl_down(s, off);
  if ((t & 63) == 0) red[t >> 6] = s;
  __syncthreads();
  if (t == 0) {
    float tot = red[0] + red[1] + red[2] + red[3];
    out[0] = tot / (float)M_E;
    float w = 0.0f;
    for (int i = 0; i < 64; ++i) w += wise_part[i];
    out[1] = w / ((float)M_E * (float)DIM);
  }
}

extern "C" void kernel_launch(void* const* d_in, const int* in_sizes, int n_in,
                              void* d_out, int out_size, void* d_ws, size_t ws_size,
                              hipStream_t stream) {
  const float* z = (const float*)d_in[0];
  const float* e = (const float*)d_in[1];
  float* out = (float*)d_out;

  char* ws = (char*)d_ws;
  unsigned short* zb = (unsigned short*)ws;                 // 8 MiB
  unsigned short* eb = (unsigned short*)(ws + 8388608);     // 2 MiB
  float* z2 = (float*)(ws + 10485760);                      // 64 KiB
  float* e2 = (float*)(ws + 10551296);                      // 16 KiB
  unsigned* d2min = (unsigned*)(ws + 10567680);             // 16 KiB
  float* wise_part = (float*)(ws + 10584064);               // 256 B
  float* zT = (float*)(ws + 11534336);                      // 16 MiB
  float* eT = (float*)(ws + 28311552);                      // 4 MiB -> 32505856

  const size_t LDS_WISE = 65536 + 3 * NB5 * 4;              // 77824 B -> 2 blocks/CU
  static int attr_done = 0;
  if (!attr_done) {
    (void)hipFuncSetAttribute((const void*)wise7_kernel,
                              hipFuncAttributeMaxDynamicSharedMemorySize, (int)LDS_WISE);
    attr_done = 1;
  }

  init_kernel<<<64, 256, 0, stream>>>(d2min, wise_part, z2, e2);
  prep_kernel<<<dim3(N_Z / 32, DIM / 32), dim3(32, 8), 0, stream>>>(z, zT, zb, z2, N_Z);
  prep_kernel<<<dim3(M_E / 32, DIM / 32), dim3(32, 8), 0, stream>>>(e, eT, eb, e2, M_E);
  gemm_min_kernel<<<dim3(32, 128), 256, 0, stream>>>(zb, eb, z2, e2, d2min);
  wise7_kernel<<<DIM, 1024, LDS_WISE, stream>>>(zT, eT, wise_part);
  final_kernel<<<1, 256, 0, stream>>>(d2min, wise_part, out);
}